// Round 16
// baseline (182.393 us; speedup 1.0000x reference)
//
#include <hip/hip_runtime.h>

// CausalAttention2d: B=2, C=512, H=W=64 (N=4096 tokens), E=512, nh=8, hd=64.
// Inputs fp32 (runtime-detected; bf16 path kept defensively). Pipeline:
//   prep(transpose+wcvt) -> gemm3 (fused if ws allows) -> attn.
// Round 26: kill attn's LDS bank conflicts (4.26M/dispatch = ~11% of attn
// cycles, constant across all r13-family variants; the one counter-backed
// lever left). Derivation: byte = row*144 + slot*16 with slot=(k+quad+row)
// &7; 144=16 mod 128 puts row and slot on the SAME 4-bank ring ->
// bank-start = 4*((2row+quad+k) mod 8); within a 16-lane quarter 2*lm mod 8
// hits only {0,2,4,6} -> 4 lanes per window (min 2) -> ~2x LDS cost. Fix:
// slot gains +(row>>3): write slot (g+row+(row>>3))&7 (rows r0+32: +4),
// reads (k4+quad+R+(R>>3))&7 -> v = (2lm+(lm>>3)+c) mod 8 covers all 8
// windows with exactly 2 lanes = conflict-free. Pure permutation; read
// formula == write formula for every (row,granule) -> bit-identical math.
// prep/gemm3 verbatim r25 (gemm gll; two gemm micro-opts were null ->
// stop). Non-attn accounting: ~95us explainable + ~75us harness reset
// machinery (fixed) -> attn is the only controllable target.

typedef __bf16 bf16;
typedef __attribute__((ext_vector_type(8))) __bf16 bf16x8;
typedef __attribute__((ext_vector_type(4))) float floatx4;

#define B_ 2
#define Cc 512
#define Nn 4096
#define Ee 512
#define NH 8
#define HD 64

#define QSCALE 0.1803368801111204f   // log2(e)/8, folded into Q

#define WSEG 262144          // 512*512
#define WTOT 787968          // 3*WSEG + 3*512

// inline dtype probe: wave-uniform, reads Wq[0:2KB] ushorts (L2-hot after
// first touch). Identical logic to the old detect_dtype kernel.
__device__ __forceinline__ int probe_f32(const unsigned short* w, int tid) {
  bool bad = false;
#pragma unroll
  for (int i = 0; i < 16; ++i) {
    unsigned u = w[(tid & 63) * 16 + i];
    float v = __uint_as_float(u << 16);
    bad |= !(v > -1024.f && v < 1024.f);  // catches big / inf / NaN
  }
  return (__ballot(bad) != 0ull) ? 1 : 0;
}

// async global->LDS 16B copy (emits global_load_lds_dwordx4).
__device__ __forceinline__ void gll16(const bf16* g, bf16* l) {
  __builtin_amdgcn_global_load_lds(
      (const __attribute__((address_space(1))) void*)g,
      (__attribute__((address_space(3))) void*)l, 16, 0, 0);
}

// load 8 consecutive elements as bf16x8 from bf16 (f32=0) or fp32 (f32=1).
__device__ __forceinline__ bf16x8 load8e(const void* base, size_t eidx, int f32) {
  if (!f32) return *(const bf16x8*)((const bf16*)base + eidx);
  const float* f = (const float*)base + eidx;
  float4 a = *(const float4*)f;
  float4 c = *(const float4*)(f + 4);
  union { bf16 h[8]; bf16x8 v; } u;
  u.h[0] = (bf16)a.x; u.h[1] = (bf16)a.y; u.h[2] = (bf16)a.z; u.h[3] = (bf16)a.w;
  u.h[4] = (bf16)c.x; u.h[5] = (bf16)c.y; u.h[6] = (bf16)c.z; u.h[7] = (bf16)c.w;
  return u.v;
}

// ---------------------------------------------------------------- prep
// z in [0,4): transpose (B,C,N)->(B,N,C) 64x64 tiles (r13 code).
// z == 4  : wcvt - fp32 W/b -> bf16 copies (512 blocks cover WTOT).
__global__ __launch_bounds__(256) void prep(
    const void* __restrict__ X0, const void* __restrict__ X1,
    bf16* __restrict__ T0, bf16* __restrict__ T1,
    const float* __restrict__ Wq, const float* __restrict__ Wk,
    const float* __restrict__ Wv, const float* __restrict__ bq,
    const float* __restrict__ bk, const float* __restrict__ bv,
    bf16* __restrict__ Wb) {
  const int f32 = probe_f32((const unsigned short*)Wq, (int)threadIdx.x);
  if (blockIdx.z == 4) {
    // ---- wcvt slice
    if (!f32) return;
    int task = (int)blockIdx.y * 64 + (int)blockIdx.x;   // 0..511
    int idx = (task * 256 + (int)threadIdx.x) * 8;
    if (idx >= WTOT) return;
    const float* src;
    int off;
    if (idx < WSEG)            { src = Wq; off = idx; }
    else if (idx < 2 * WSEG)   { src = Wk; off = idx - WSEG; }
    else if (idx < 3 * WSEG)   { src = Wv; off = idx - 2 * WSEG; }
    else if (idx < 3 * WSEG + 512)  { src = bq; off = idx - 3 * WSEG; }
    else if (idx < 3 * WSEG + 1024) { src = bk; off = idx - 3 * WSEG - 512; }
    else                            { src = bv; off = idx - 3 * WSEG - 1024; }
    float4 a = *(const float4*)(src + off);
    float4 c = *(const float4*)(src + off + 4);
    union { bf16 h[8]; bf16x8 v; } u;
    u.h[0] = (bf16)a.x; u.h[1] = (bf16)a.y; u.h[2] = (bf16)a.z; u.h[3] = (bf16)a.w;
    u.h[4] = (bf16)c.x; u.h[5] = (bf16)c.y; u.h[6] = (bf16)c.z; u.h[7] = (bf16)c.w;
    *(bf16x8*)(Wb + idx) = u.v;
    return;
  }
  // ---- transpose slice (r13 verbatim)
  __shared__ __align__(16) bf16 T[64 * 64];
  const int z = blockIdx.z;
  const int bb = z & 1;
  const void* src = (z >> 1) ? X1 : X0;
  bf16* dst = (z >> 1) ? T1 : T0;
  const int n0 = blockIdx.x * 64, c0 = blockIdx.y * 64;
  const int t = threadIdx.x;
  const size_t sbase = ((size_t)bb * Cc + c0) * (size_t)Nn + n0;

#pragma unroll
  for (int it = 0; it < 2; ++it) {
    int task = t + it * 256;            // 512 tasks: 64 c-rows x 8 n-granules
    int crow = task >> 3, gr = task & 7;
    bf16x8 v = load8e(src, sbase + (size_t)crow * Nn + gr * 8, f32);
    int slot = gr ^ (crow & 7);
    *(bf16x8*)&T[crow * 64 + slot * 8] = v;
  }
  __syncthreads();
  const int nrow = t & 63, cp = t >> 6;
  bf16* db = dst + ((size_t)bb * Nn + n0 + nrow) * Cc + c0;
#pragma unroll
  for (int it = 0; it < 2; ++it) {
    int cg = cp * 2 + it;               // c-granule 0..7
    union { bf16 h[8]; bf16x8 v; } u;
#pragma unroll
    for (int j = 0; j < 8; ++j) {
      int c = cg * 8 + j;
      int slot = (nrow >> 3) ^ (c & 7);
      u.h[j] = T[c * 64 + slot * 8 + (nrow & 7)];
    }
    *(bf16x8*)(db + cg * 8) = u.v;
  }
}

// ---------------------------------------------------------------- gemm3
// Q/K/V projection; (blockIdx.z + zoff): 0,1 = Q(b); 2,3 = K(b); 4,5 = V(b).
// Fused single launch (z=6, zoff=0) when Vh does NOT alias Xtq; else two
// launches. Out[m][n] = (sum_k A[m][k]*Bt[n][k] + bias) * scaleOut, K=512.
// r24 structure: staging via global_load_lds width=16. SA=32 (dest = wave
// base + lane*16B); granule rotate-swizzle: slot s of row r holds granule
// (s+r)&3, frag read of granule q at slot (q-r)&3. Per step: issue 4 gll
// for t+1 into buf^1, ds_read frags of t, 16 MFMA, barrier.
__global__ __launch_bounds__(256) void gemm3(
    const bf16* __restrict__ Xtq, const bf16* __restrict__ Xtk,
    const void* __restrict__ Wq0, const bf16* __restrict__ Wqb,
    const void* __restrict__ Wk0, const bf16* __restrict__ Wkb,
    const void* __restrict__ Wv0, const bf16* __restrict__ Wvb,
    const void* __restrict__ bq0, const bf16* __restrict__ bqb,
    const void* __restrict__ bk0, const bf16* __restrict__ bkb,
    const void* __restrict__ bv0, const bf16* __restrict__ bvb,
    bf16* __restrict__ Qt, bf16* __restrict__ Kt, bf16* __restrict__ Vh,
    int zoff) {
  const int f32 = probe_f32((const unsigned short*)Wq0, (int)threadIdx.x);
  const int z = (int)blockIdx.z + zoff;
  const int op = z >> 1, b = z & 1;
  const bf16 *A, *Bt, *bias;
  bf16* Out;
  long sAb, sBb, sOb;
  int Nq, biasOnM, m0, n0;
  float scaleOut;
  if (op == 0) {
    A = Xtq; sAb = (long)Nn * Cc;
    Bt = f32 ? Wqb : (const bf16*)Wq0; sBb = 0;
    bias = f32 ? bqb : (const bf16*)bq0;
    Out = Qt; sOb = (long)Nn * Ee; Nq = Ee; biasOnM = 0; scaleOut = QSCALE;
    m0 = blockIdx.x * 128; n0 = blockIdx.y * 128;
  } else if (op == 1) {
    A = Xtk; sAb = (long)Nn * Cc;
    Bt = f32 ? Wkb : (const bf16*)Wk0; sBb = 0;
    bias = f32 ? bkb : (const bf16*)bk0;
    Out = Kt; sOb = (long)Nn * Ee; Nq = Ee; biasOnM = 0; scaleOut = 1.0f;
    m0 = blockIdx.x * 128; n0 = blockIdx.y * 128;
  } else {
    A = f32 ? Wvb : (const bf16*)Wv0; sAb = 0;
    Bt = Xtk; sBb = (long)Nn * Cc;
    bias = f32 ? bvb : (const bf16*)bv0;
    Out = Vh; sOb = (long)Ee * Nn; Nq = Nn; biasOnM = 1; scaleOut = 1.0f;
    m0 = blockIdx.y * 128;             // M = Ee = 512 -> 4 row-blocks
    n0 = blockIdx.x * 128;             // N = Nn = 4096 -> 32 col-blocks
  }
  constexpr int K = 512;
  constexpr int SA = 32;
  __shared__ __align__(16) bf16 As[2][128 * SA];
  __shared__ __align__(16) bf16 Bs[2][128 * SA];
  const int tid = threadIdx.x;
  const int lane = tid & 63, wave = tid >> 6;
  const int quad = lane >> 4, lm = lane & 15;
  const bf16* Ab = A + (size_t)b * sAb;
  const bf16* Bb = Bt + (size_t)b * sBb;
  bf16* Ob = Out + (size_t)b * sOb;

  const int arow = tid >> 2, ag = tid & 3;   // 64 rows x 4 k-granules
  const int gsw = (ag + arow) & 3;           // swizzled granule to fetch
                                             // (row+64: same &3, 64%4==0)
  floatx4 acc[2][8];
#pragma unroll
  for (int i = 0; i < 2; ++i)
#pragma unroll
    for (int j = 0; j < 8; ++j) acc[i][j] = (floatx4){0.f, 0.f, 0.f, 0.f};

  // async staging: slot ag of row r receives granule (ag + r)&3
#define ISSUE(step, c_)                                                      \
  do {                                                                       \
    const int k0_ = (step) * 32 + gsw * 8;                                   \
    gll16(Ab + (size_t)(m0 + arow) * K + k0_,                                \
          &As[c_][arow * SA + ag * 8]);                                      \
    gll16(Ab + (size_t)(m0 + 64 + arow) * K + k0_,                           \
          &As[c_][(64 + arow) * SA + ag * 8]);                               \
    gll16(Bb + (size_t)(n0 + arow) * K + k0_,                                \
          &Bs[c_][arow * SA + ag * 8]);                                      \
    gll16(Bb + (size_t)(n0 + 64 + arow) * K + k0_,                           \
          &Bs[c_][(64 + arow) * SA + ag * 8]);                               \
  } while (0)

  ISSUE(0, 0);
  __syncthreads();       // vmcnt drained -> buf0 ready

  for (int kk = 0; kk < 16; ++kk) {
    const int c = kk & 1;
    if (kk + 1 < 16) ISSUE(kk + 1, c ^ 1);   // async into other buffer
    bf16x8 af[2];
#pragma unroll
    for (int mf = 0; mf < 2; ++mf) {
      int r = wave * 32 + mf * 16 + lm;
      int sa = (quad - r) & 3;               // granule quad at slot (q-r)&3
      af[mf] = *(const bf16x8*)&As[c][r * SA + sa * 8];
    }
#pragma unroll
    for (int nf = 0; nf < 8; ++nf) {
      int rn = nf * 16 + lm;
      int sb = (quad - rn) & 3;
      bf16x8 bfr = *(const bf16x8*)&Bs[c][rn * SA + sb * 8];
      acc[0][nf] = __builtin_amdgcn_mfma_f32_16x16x32_bf16(
          af[0], bfr, acc[0][nf], 0, 0, 0);
      acc[1][nf] = __builtin_amdgcn_mfma_f32_16x16x32_bf16(
          af[1], bfr, acc[1][nf], 0, 0, 0);
    }
    __syncthreads();     // buf c reads done; async loads for c^1 drained
  }
#undef ISSUE

#pragma unroll
  for (int mf = 0; mf < 2; ++mf) {
#pragma unroll
    for (int nf = 0; nf < 8; ++nf) {
      int col = n0 + nf * 16 + lm;
      float bn = biasOnM ? 0.f : (float)bias[col];
#pragma unroll
      for (int r = 0; r < 4; ++r) {
        int rowg = m0 + wave * 32 + mf * 16 + quad * 4 + r;
        float bv = biasOnM ? (float)bias[rowg] : bn;
        Ob[(size_t)rowg * Nq + col] = (bf16)((acc[mf][nf][r] + bv) * scaleOut);
      }
    }
  }
}

// single v_exp_f32 with compiler-managed hazards (s in [-13,7]: no guards
// needed; denormal/overflow impossible).
__device__ __forceinline__ float fast_exp2(float x) {
  return __builtin_amdgcn_exp2f(x);
}
// round-half-up bf16 of two floats packed into one u32 (lo = a, hi = b).
__device__ __forceinline__ unsigned pack_bf16_2(float a, float b) {
  unsigned ua = __float_as_uint(a) + 0x8000u;
  unsigned ub = __float_as_uint(b) + 0x8000u;
  return (ua >> 16) | (ub & 0xFFFF0000u);
}

// ---------------------------------------------------------------- attention
// r13 structure + r26 conflict-free slot swizzle. Grid (64, NH, B) = 1024
// blocks, 4 waves x 16 q. Remap: xcd=L&7, slot=L>>3, half=slot>>6,
// sp=slot&63; p=half?63-sp:sp; (b,h)=xcd*2+half -> constant 130
// tile-units/CU, 2 heads/XCD (2MB K/V fits 4MB L2). Slot formula now
// (g + row + (row>>3))&7 on writes (rows r0+32: +4) and
// (k4 + quad + R + (R>>3))&7 on reads -> each 16-lane quarter spreads its
// b128 accesses 2-per-window = conflict-free (was 4 -> ~2x LDS cost).
// 2-deep register prefetch, setprio, P=2^s VALU-diet softmax.
__global__ __launch_bounds__(256, 4) void attn(
    const bf16* __restrict__ Qt, const bf16* __restrict__ Kt,
    const bf16* __restrict__ Ve, void* __restrict__ Out,
    const unsigned short* __restrict__ wdet) {
  const int tid = threadIdx.x, lane = tid & 63, w = tid >> 6;
  const int f32 = probe_f32(wdet, tid);
  constexpr int SK = 72;
  __shared__ __align__(16) bf16 Ks[2][64 * SK];   // [buf][key][e]
  __shared__ __align__(16) bf16 Vs[2][64 * SK];   // [buf][d][key]
  const int quad = lane >> 4, lm = lane & 15;

  const int L = (int)blockIdx.x + 64 * (int)blockIdx.y + 512 * (int)blockIdx.z;
  const int xcd = L & 7, slot0 = L >> 3;
  const int half = slot0 >> 6, sp = slot0 & 63;
  const int p = half ? 63 - sp : sp;
  const int hp = xcd * 2 + half;       // 0..15
  const int b = hp >> 3, h = hp & 7;

  const int Q0 = p * 64;
  const int qbase = Q0 + w * 16;
  const int last = p;                  // tiles 0..p

  // Q B-frags (persistent): qf[ks] = B[e=quad*8+j+ks*32][q=lm]
  bf16x8 qf[2];
  {
    const bf16* qp =
        Qt + ((size_t)b * Nn + qbase + lm) * Ee + h * HD + quad * 8;
    qf[0] = *(const bf16x8*)qp;
    qf[1] = *(const bf16x8*)(qp + 32);
  }
  floatx4 accO[4];
#pragma unroll
  for (int df = 0; df < 4; ++df) accO[df] = (floatx4){0.f, 0.f, 0.f, 0.f};
  float lsum = 0.f;

  // staging: r0 = tid>>3 in [0,32), g = tid&7; rows r0 and r0+32.
  // slot = (g + row + (row>>3))&7; row r0+32 -> +36 = +4 mod 8.
  const int r0 = tid >> 3, g = tid & 7;
  const int sA = ((g + r0 + (r0 >> 3)) & 7) * 8;
  const int sB = ((g + r0 + (r0 >> 3) + 4) & 7) * 8;
  const bf16* kp0 = Kt + ((size_t)b * Nn + r0) * Ee + h * HD + g * 8;
  const bf16* kp1 = kp0 + (size_t)32 * Ee;
  const bf16* vp0 = Ve + ((size_t)b * Ee + h * HD + r0) * Nn + g * 8;
  const bf16* vp1 = vp0 + (size_t)32 * Nn;

  // QK A-row permutation base: row R = quad*8 + 4*(f&1) + (lm&3) + 32*(f>>1)
  const int rbase = ((lm >> 2) << 3) | (lm & 3);

  // two register prefetch sets; all indices compile-time (rule #20)
  bf16x8 ka[2], kb[2], va[2], vb[2];
#define LOADT(s)                                                   \
  do {                                                             \
    ka[s] = *(const bf16x8*)kp0; kb[s] = *(const bf16x8*)kp1;      \
    va[s] = *(const bf16x8*)vp0; vb[s] = *(const bf16x8*)vp1;      \
    kp0 += (size_t)64 * Ee; kp1 += (size_t)64 * Ee;                \
    vp0 += 64; vp1 += 64;                                          \
  } while (0)
#define STAGET(s, buf)                                             \
  do {                                                             \
    *(bf16x8*)&Ks[buf][r0 * SK + sA] = ka[s];                      \
    *(bf16x8*)&Ks[buf][(r0 + 32) * SK + sB] = kb[s];               \
    *(bf16x8*)&Vs[buf][r0 * SK + sA] = va[s];                      \
    *(bf16x8*)&Vs[buf][(r0 + 32) * SK + sB] = vb[s];               \
  } while (0)

  // prologue: tile0 -> set0 -> LDS[0]; tile1 -> set1 (stays in regs)
  LOADT(0);
  if (last >= 1) LOADT(1);
  STAGET(0, 0);          // vmcnt waits only on set0's 4 loads
  __syncthreads();

#pragma unroll 1
  for (int kt = 0; kt <= last; kt += 2) {
#pragma unroll
    for (int u = 0; u < 2; ++u) {            // u is compile-time after unroll
      const int t = kt + u;
      if (u == 1 && t > last) break;         // block-uniform tail skip
      const int k0 = t * 64;
      if (t + 2 <= last) LOADT(u);           // 2-deep prefetch
      const bool skip = k0 > qbase + 15;     // wave-uniform: fully masked

      bf16x8 pb[2];
      if (!skip) {
        // S^T = K Q^T with permuted A-rows
        floatx4 accS[4];
#pragma unroll
        for (int f = 0; f < 4; ++f) accS[f] = (floatx4){0.f, 0.f, 0.f, 0.f};
        __builtin_amdgcn_s_setprio(1);
#pragma unroll
        for (int ks = 0; ks < 2; ++ks)
#pragma unroll
          for (int f = 0; f < 4; ++f) {
            const int R = rbase + ((f & 1) << 2) + ((f >> 1) << 5);
            const int sl = (ks * 4 + quad + R + (R >> 3)) & 7;
            bf16x8 ak = *(const bf16x8*)&Ks[u][R * SK + sl * 8];
            accS[f] = __builtin_amdgcn_mfma_f32_16x16x32_bf16(
                ak, qf[ks], accS[f], 0, 0, 0);
          }
        __builtin_amdgcn_s_setprio(0);
        // softmax + pack: key = k0 + g2*32 + quad*8 + jp*2; q = qbase+lm
        const bool maskt = (k0 + 63 > qbase);
        if (!maskt) {
          // mask-free fast path (vast majority of tiles)
          float la = 0.f, lb = 0.f;
#pragma unroll
          for (int g2 = 0; g2 < 2; ++g2) {
            union { unsigned pk[4]; bf16x8 v; } uu;
#pragma unroll
            for (int jp = 0; jp < 4; ++jp) {
              const int fidx = g2 * 2 + (jp >> 1);
              const int re = (jp & 1) * 2;
              float p0 = fast_exp2(accS[fidx][re]);
              float p1 = fast_exp2(accS[fidx][re + 1]);
              la += p0; lb += p1;
              uu.pk[jp] = pack_bf16_2(p0, p1);
            }
            pb[g2] = uu.v;
          }
          lsum += la + lb;
        } else {
          // diagonal tile: per-element causal zeroing
          const int qg = qbase + lm;
          float la = 0.f, lb = 0.f;
#pragma unroll
          for (int g2 = 0; g2 < 2; ++g2) {
            union { unsigned pk[4]; bf16x8 v; } uu;
#pragma unroll
            for (int jp = 0; jp < 4; ++jp) {
              const int fidx = g2 * 2 + (jp >> 1);
              const int re = (jp & 1) * 2;
              const int key0 = k0 + g2 * 32 + quad * 8 + jp * 2;
              float p0 = fast_exp2(accS[fidx][re]);
              float p1 = fast_exp2(accS[fidx][re + 1]);
              if (key0 > qg) p0 = 0.f;
              if (key0 + 1 > qg) p1 = 0.f;
              la += p0; lb += p1;
              uu.pk[jp] = pack_bf16_2(p0, p1);
            }
            pb[g2] = uu.v;
          }
          lsum += la + lb;
        }
      }
      // stage tile t+1 (reg set u^1) into the other LDS buffer; vmcnt here
      // waits only on set u^1's loads (issued >1 full tile ago)
      if (t + 1 <= last) STAGET(u ^ 1, u ^ 1);
      if (!skip) {
        // O^T += V^T P^T at K=32: A[d=df*16+lm][key=g2*32+quad*8+j] (b128)
        __builtin_amdgcn_s_setprio(1);
#pragma unroll
        for (int g2 = 0; g2 < 2; ++g2)
#pragma unroll
          for (int df = 0; df < 4; ++df) {
            const int Rv = df * 16 + lm;
            const int sl = (g2 * 4 + quad + Rv + (Rv >> 3)) & 7;
            bf16x8 av = *(const bf16x8*)&Vs[u][Rv * SK + sl * 8];
            accO[df] = __builtin_amdgcn_mfma_f32_16x16x32_bf16(
                av, pb[g2], accO[df], 0, 0, 0);
          }
        __builtin_amdgcn_s_setprio(0);
      }
      __syncthreads();  // buf u reads done everywhere; buf u^1 fully staged
    }
  }
#undef LOADT
#undef STAGET

  // l(q) split across the 4 quads -> reduce lanes lm+16k
  lsum += __shfl_xor(lsum, 16);
  lsum += __shfl_xor(lsum, 32);

  // epilogue: accO[df] rows d = df*16+quad*4+r, col q = qbase+lm
  const float inv = 1.0f / lsum;
  const int qg = qbase + lm;
#pragma unroll
  for (int df = 0; df < 4; ++df) {
#pragma unroll
    for (int r = 0; r < 4; ++r) {
      int d = h * HD + df * 16 + quad * 4 + r;
      size_t off = ((size_t)b * Ee + d) * Nn + qg;
      if (!f32) ((bf16*)Out)[off] = (bf16)(accO[df][r] * inv);
      else      ((float*)Out)[off] = accO[df][r] * inv;
    }
  }
}

// ---------------------------------------------------------------- launch
extern "C" void kernel_launch(void* const* d_in, const int* in_sizes, int n_in,
                              void* d_out, int out_size, void* d_ws,
                              size_t ws_size, hipStream_t stream) {
  const void* q  = d_in[0];
  const void* k  = d_in[1];
  const void* Wq = d_in[2];
  const void* bq = d_in[3];
  const void* Wk = d_in[4];
  const void* bk = d_in[5];
  const void* Wv = d_in[6];
  const void* bv = d_in[7];

  const size_t SZ = (size_t)B_ * Nn * Cc;  // 4M elems = 8MB bf16 per region
  // ws: [pad 1KB][Xtq 8MB][Qt 8MB][Kt 8MB][Vh 8MB if room].
  // d_out (16MB when fp32): lower 8MB = Xtk scratch, upper 8MB = bf16 W/bias
  // copies; both dead before attn writes the final output.
  bf16* Xtq  = (bf16*)((char*)d_ws + 1024);
  bf16* Qt   = Xtq + SZ;
  bf16* Kt   = Qt + SZ;
  bf16* Xtk  = (bf16*)d_out;
  bf16* Wb   = (bf16*)((char*)d_out + 8 * 1024 * 1024);
  bf16* Wqb = Wb,            *Wkb = Wb + WSEG,    *Wvb = Wb + 2 * WSEG;
  bf16* bqb = Wb + 3 * WSEG, *bkb = bqb + 512,    *bvb = bqb + 1024;

  // Vh: its own region when the workspace is big enough -> one fused gemm
  // launch (no Q/K vs V serialization); else alias Xtq + two launches.
  const size_t need = 1024 + 4 * SZ * sizeof(bf16);
  const bool sep = ws_size >= need;
  bf16* Vh = sep ? (Kt + SZ) : Xtq;

  prep<<<dim3(64, 8, 5), 256, 0, stream>>>(
      q, k, Xtq, Xtk,
      (const float*)Wq, (const float*)Wk, (const float*)Wv,
      (const float*)bq, (const float*)bk, (const float*)bv, Wb);
  if (sep) {
    gemm3<<<dim3(32, 4, 6), 256, 0, stream>>>(
        Xtq, Xtk, Wq, Wqb, Wk, Wkb, Wv, Wvb,
        bq, bqb, bk, bkb, bv, bvb, Qt, Kt, Vh, 0);
  } else {
    // Q+K projections (read Xtq/Xtk; no aliasing within the launch)
    gemm3<<<dim3(32, 4, 4), 256, 0, stream>>>(
        Xtq, Xtk, Wq, Wqb, Wk, Wkb, Wv, Wvb,
        bq, bqb, bk, bkb, bv, bvb, Qt, Kt, Vh, 0);
    // V projection (writes Vh == Xtq region) - separate launch, serialized
    gemm3<<<dim3(32, 4, 2), 256, 0, stream>>>(
        Xtq, Xtk, Wq, Wqb, Wk, Wkb, Wv, Wvb,
        bq, bqb, bk, bkb, bv, bvb, Qt, Kt, Vh, 4);
  }
  attn<<<dim3(64, NH, B_), 256, 0, stream>>>(
      Qt, Kt, Vh, d_out, (const unsigned short*)Wq);
}

// Round 17
// 175.776 us; speedup vs baseline: 1.0376x; 1.0376x over previous
//
#include <hip/hip_runtime.h>

// CausalAttention2d: B=2, C=512, H=W=64 (N=4096 tokens), E=512, nh=8, hd=64.
// Inputs fp32 (runtime-detected; bf16 path kept defensively). Pipeline:
//   prep(transpose+wcvt) -> gemm3 (fused if ws allows) -> attn.
// Round 27: REVERT to r25 (best verified, 175.9us). r26's bank-swizzle
// "fix" doubled conflicts (4.26M->8.52M) and cost 5us - the quarter-window
// bank model is falsified; that lever is closed without disasm evidence.
// State of knowledge: attn's 62us plateau survived 7 structural rewrites
// (imbalance/prefetch/occupancy/LDS-removal/key-split/chain-halving/
// barrier-free all refuted by A/B); non-attn = ~95us explainable work +
// ~75us fixed harness reset; two gemm micro-opts null. Wins that stuck:
// CU pairing (r11), 2-deep prefetch (r12), XCD/L2 pinning + QBLK=64 (r13),
// launch fusion + inline dtype probe (r22/r23): 224 -> 175.9us.

typedef __bf16 bf16;
typedef __attribute__((ext_vector_type(8))) __bf16 bf16x8;
typedef __attribute__((ext_vector_type(4))) float floatx4;

#define B_ 2
#define Cc 512
#define Nn 4096
#define Ee 512
#define NH 8
#define HD 64

#define QSCALE 0.1803368801111204f   // log2(e)/8, folded into Q

#define WSEG 262144          // 512*512
#define WTOT 787968          // 3*WSEG + 3*512

// inline dtype probe: wave-uniform, reads Wq[0:2KB] ushorts (L2-hot after
// first touch). Identical logic to the old detect_dtype kernel.
__device__ __forceinline__ int probe_f32(const unsigned short* w, int tid) {
  bool bad = false;
#pragma unroll
  for (int i = 0; i < 16; ++i) {
    unsigned u = w[(tid & 63) * 16 + i];
    float v = __uint_as_float(u << 16);
    bad |= !(v > -1024.f && v < 1024.f);  // catches big / inf / NaN
  }
  return (__ballot(bad) != 0ull) ? 1 : 0;
}

// async global->LDS 16B copy (emits global_load_lds_dwordx4).
__device__ __forceinline__ void gll16(const bf16* g, bf16* l) {
  __builtin_amdgcn_global_load_lds(
      (const __attribute__((address_space(1))) void*)g,
      (__attribute__((address_space(3))) void*)l, 16, 0, 0);
}

// load 8 consecutive elements as bf16x8 from bf16 (f32=0) or fp32 (f32=1).
__device__ __forceinline__ bf16x8 load8e(const void* base, size_t eidx, int f32) {
  if (!f32) return *(const bf16x8*)((const bf16*)base + eidx);
  const float* f = (const float*)base + eidx;
  float4 a = *(const float4*)f;
  float4 c = *(const float4*)(f + 4);
  union { bf16 h[8]; bf16x8 v; } u;
  u.h[0] = (bf16)a.x; u.h[1] = (bf16)a.y; u.h[2] = (bf16)a.z; u.h[3] = (bf16)a.w;
  u.h[4] = (bf16)c.x; u.h[5] = (bf16)c.y; u.h[6] = (bf16)c.z; u.h[7] = (bf16)c.w;
  return u.v;
}

// ---------------------------------------------------------------- prep
// z in [0,4): transpose (B,C,N)->(B,N,C) 64x64 tiles (r13 code).
// z == 4  : wcvt - fp32 W/b -> bf16 copies (512 blocks cover WTOT).
__global__ __launch_bounds__(256) void prep(
    const void* __restrict__ X0, const void* __restrict__ X1,
    bf16* __restrict__ T0, bf16* __restrict__ T1,
    const float* __restrict__ Wq, const float* __restrict__ Wk,
    const float* __restrict__ Wv, const float* __restrict__ bq,
    const float* __restrict__ bk, const float* __restrict__ bv,
    bf16* __restrict__ Wb) {
  const int f32 = probe_f32((const unsigned short*)Wq, (int)threadIdx.x);
  if (blockIdx.z == 4) {
    // ---- wcvt slice
    if (!f32) return;
    int task = (int)blockIdx.y * 64 + (int)blockIdx.x;   // 0..511
    int idx = (task * 256 + (int)threadIdx.x) * 8;
    if (idx >= WTOT) return;
    const float* src;
    int off;
    if (idx < WSEG)            { src = Wq; off = idx; }
    else if (idx < 2 * WSEG)   { src = Wk; off = idx - WSEG; }
    else if (idx < 3 * WSEG)   { src = Wv; off = idx - 2 * WSEG; }
    else if (idx < 3 * WSEG + 512)  { src = bq; off = idx - 3 * WSEG; }
    else if (idx < 3 * WSEG + 1024) { src = bk; off = idx - 3 * WSEG - 512; }
    else                            { src = bv; off = idx - 3 * WSEG - 1024; }
    float4 a = *(const float4*)(src + off);
    float4 c = *(const float4*)(src + off + 4);
    union { bf16 h[8]; bf16x8 v; } u;
    u.h[0] = (bf16)a.x; u.h[1] = (bf16)a.y; u.h[2] = (bf16)a.z; u.h[3] = (bf16)a.w;
    u.h[4] = (bf16)c.x; u.h[5] = (bf16)c.y; u.h[6] = (bf16)c.z; u.h[7] = (bf16)c.w;
    *(bf16x8*)(Wb + idx) = u.v;
    return;
  }
  // ---- transpose slice (r13 verbatim)
  __shared__ __align__(16) bf16 T[64 * 64];
  const int z = blockIdx.z;
  const int bb = z & 1;
  const void* src = (z >> 1) ? X1 : X0;
  bf16* dst = (z >> 1) ? T1 : T0;
  const int n0 = blockIdx.x * 64, c0 = blockIdx.y * 64;
  const int t = threadIdx.x;
  const size_t sbase = ((size_t)bb * Cc + c0) * (size_t)Nn + n0;

#pragma unroll
  for (int it = 0; it < 2; ++it) {
    int task = t + it * 256;            // 512 tasks: 64 c-rows x 8 n-granules
    int crow = task >> 3, gr = task & 7;
    bf16x8 v = load8e(src, sbase + (size_t)crow * Nn + gr * 8, f32);
    int slot = gr ^ (crow & 7);
    *(bf16x8*)&T[crow * 64 + slot * 8] = v;
  }
  __syncthreads();
  const int nrow = t & 63, cp = t >> 6;
  bf16* db = dst + ((size_t)bb * Nn + n0 + nrow) * Cc + c0;
#pragma unroll
  for (int it = 0; it < 2; ++it) {
    int cg = cp * 2 + it;               // c-granule 0..7
    union { bf16 h[8]; bf16x8 v; } u;
#pragma unroll
    for (int j = 0; j < 8; ++j) {
      int c = cg * 8 + j;
      int slot = (nrow >> 3) ^ (c & 7);
      u.h[j] = T[c * 64 + slot * 8 + (nrow & 7)];
    }
    *(bf16x8*)(db + cg * 8) = u.v;
  }
}

// ---------------------------------------------------------------- gemm3
// Q/K/V projection; (blockIdx.z + zoff): 0,1 = Q(b); 2,3 = K(b); 4,5 = V(b).
// Fused single launch (z=6, zoff=0) when Vh does NOT alias Xtq; else two
// launches. Out[m][n] = (sum_k A[m][k]*Bt[n][k] + bias) * scaleOut, K=512.
// Staging via global_load_lds width=16. SA=32 (dest = wave base +
// lane*16B); granule rotate-swizzle: slot s of row r holds granule (s+r)&3
// (global src pre-swizzled), frag read of granule q at slot (q-r)&3.
// Per step: issue 4 gll for step t+1 into buf^1, ds_read frags of step t,
// 16 MFMA, barrier (drains the async loads; m97 structure).
__global__ __launch_bounds__(256) void gemm3(
    const bf16* __restrict__ Xtq, const bf16* __restrict__ Xtk,
    const void* __restrict__ Wq0, const bf16* __restrict__ Wqb,
    const void* __restrict__ Wk0, const bf16* __restrict__ Wkb,
    const void* __restrict__ Wv0, const bf16* __restrict__ Wvb,
    const void* __restrict__ bq0, const bf16* __restrict__ bqb,
    const void* __restrict__ bk0, const bf16* __restrict__ bkb,
    const void* __restrict__ bv0, const bf16* __restrict__ bvb,
    bf16* __restrict__ Qt, bf16* __restrict__ Kt, bf16* __restrict__ Vh,
    int zoff) {
  const int f32 = probe_f32((const unsigned short*)Wq0, (int)threadIdx.x);
  const int z = (int)blockIdx.z + zoff;
  const int op = z >> 1, b = z & 1;
  const bf16 *A, *Bt, *bias;
  bf16* Out;
  long sAb, sBb, sOb;
  int Nq, biasOnM, m0, n0;
  float scaleOut;
  if (op == 0) {
    A = Xtq; sAb = (long)Nn * Cc;
    Bt = f32 ? Wqb : (const bf16*)Wq0; sBb = 0;
    bias = f32 ? bqb : (const bf16*)bq0;
    Out = Qt; sOb = (long)Nn * Ee; Nq = Ee; biasOnM = 0; scaleOut = QSCALE;
    m0 = blockIdx.x * 128; n0 = blockIdx.y * 128;
  } else if (op == 1) {
    A = Xtk; sAb = (long)Nn * Cc;
    Bt = f32 ? Wkb : (const bf16*)Wk0; sBb = 0;
    bias = f32 ? bkb : (const bf16*)bk0;
    Out = Kt; sOb = (long)Nn * Ee; Nq = Ee; biasOnM = 0; scaleOut = 1.0f;
    m0 = blockIdx.x * 128; n0 = blockIdx.y * 128;
  } else {
    A = f32 ? Wvb : (const bf16*)Wv0; sAb = 0;
    Bt = Xtk; sBb = (long)Nn * Cc;
    bias = f32 ? bvb : (const bf16*)bv0;
    Out = Vh; sOb = (long)Ee * Nn; Nq = Nn; biasOnM = 1; scaleOut = 1.0f;
    m0 = blockIdx.y * 128;             // M = Ee = 512 -> 4 row-blocks
    n0 = blockIdx.x * 128;             // N = Nn = 4096 -> 32 col-blocks
  }
  constexpr int K = 512;
  constexpr int SA = 32;
  __shared__ __align__(16) bf16 As[2][128 * SA];
  __shared__ __align__(16) bf16 Bs[2][128 * SA];
  const int tid = threadIdx.x;
  const int lane = tid & 63, wave = tid >> 6;
  const int quad = lane >> 4, lm = lane & 15;
  const bf16* Ab = A + (size_t)b * sAb;
  const bf16* Bb = Bt + (size_t)b * sBb;
  bf16* Ob = Out + (size_t)b * sOb;

  const int arow = tid >> 2, ag = tid & 3;   // 64 rows x 4 k-granules
  const int gsw = (ag + arow) & 3;           // swizzled granule to fetch
                                             // (row+64: same &3, 64%4==0)
  floatx4 acc[2][8];
#pragma unroll
  for (int i = 0; i < 2; ++i)
#pragma unroll
    for (int j = 0; j < 8; ++j) acc[i][j] = (floatx4){0.f, 0.f, 0.f, 0.f};

  // async staging: slot ag of row r receives granule (ag + r)&3
#define ISSUE(step, c_)                                                      \
  do {                                                                       \
    const int k0_ = (step) * 32 + gsw * 8;                                   \
    gll16(Ab + (size_t)(m0 + arow) * K + k0_,                                \
          &As[c_][arow * SA + ag * 8]);                                      \
    gll16(Ab + (size_t)(m0 + 64 + arow) * K + k0_,                           \
          &As[c_][(64 + arow) * SA + ag * 8]);                               \
    gll16(Bb + (size_t)(n0 + arow) * K + k0_,                                \
          &Bs[c_][arow * SA + ag * 8]);                                      \
    gll16(Bb + (size_t)(n0 + 64 + arow) * K + k0_,                           \
          &Bs[c_][(64 + arow) * SA + ag * 8]);                               \
  } while (0)

  ISSUE(0, 0);
  __syncthreads();       // vmcnt drained -> buf0 ready

  for (int kk = 0; kk < 16; ++kk) {
    const int c = kk & 1;
    if (kk + 1 < 16) ISSUE(kk + 1, c ^ 1);   // async into other buffer
    bf16x8 af[2];
#pragma unroll
    for (int mf = 0; mf < 2; ++mf) {
      int r = wave * 32 + mf * 16 + lm;
      int sa = (quad - r) & 3;               // granule quad at slot (q-r)&3
      af[mf] = *(const bf16x8*)&As[c][r * SA + sa * 8];
    }
#pragma unroll
    for (int nf = 0; nf < 8; ++nf) {
      int rn = nf * 16 + lm;
      int sb = (quad - rn) & 3;
      bf16x8 bfr = *(const bf16x8*)&Bs[c][rn * SA + sb * 8];
      acc[0][nf] = __builtin_amdgcn_mfma_f32_16x16x32_bf16(
          af[0], bfr, acc[0][nf], 0, 0, 0);
      acc[1][nf] = __builtin_amdgcn_mfma_f32_16x16x32_bf16(
          af[1], bfr, acc[1][nf], 0, 0, 0);
    }
    __syncthreads();     // buf c reads done; async loads for c^1 drained
  }
#undef ISSUE

#pragma unroll
  for (int mf = 0; mf < 2; ++mf) {
#pragma unroll
    for (int nf = 0; nf < 8; ++nf) {
      int col = n0 + nf * 16 + lm;
      float bn = biasOnM ? 0.f : (float)bias[col];
#pragma unroll
      for (int r = 0; r < 4; ++r) {
        int rowg = m0 + wave * 32 + mf * 16 + quad * 4 + r;
        float bv = biasOnM ? (float)bias[rowg] : bn;
        Ob[(size_t)rowg * Nq + col] = (bf16)((acc[mf][nf][r] + bv) * scaleOut);
      }
    }
  }
}

// single v_exp_f32 with compiler-managed hazards (s in [-13,7]: no guards
// needed; denormal/overflow impossible).
__device__ __forceinline__ float fast_exp2(float x) {
  return __builtin_amdgcn_exp2f(x);
}
// round-half-up bf16 of two floats packed into one u32 (lo = a, hi = b).
__device__ __forceinline__ unsigned pack_bf16_2(float a, float b) {
  unsigned ua = __float_as_uint(a) + 0x8000u;
  unsigned ub = __float_as_uint(b) + 0x8000u;
  return (ua >> 16) | (ub & 0xFFFF0000u);
}

// ---------------------------------------------------------------- attention
// r13 VERBATIM (62-63us) + inline dtype probe. Grid (64, NH, B) = 1024
// blocks, 4 waves x 16 q. Remap: xcd=L&7, slot=L>>3, half=slot>>6,
// sp=slot&63; p=half?63-sp:sp; (b,h)=xcd*2+half -> constant 130
// tile-units/CU, 2 heads/XCD (2MB K/V fits 4MB L2). Per 64-key tile: QK
// with permuted A-rows (S^T per lane = exact PV B-frag, in-register P);
// V reads b128; rotate swizzle slot=(g+row)&7 on SK=72. 2-deep register
// prefetch, setprio, P=2^s VALU-diet softmax.
__global__ __launch_bounds__(256, 4) void attn(
    const bf16* __restrict__ Qt, const bf16* __restrict__ Kt,
    const bf16* __restrict__ Ve, void* __restrict__ Out,
    const unsigned short* __restrict__ wdet) {
  const int tid = threadIdx.x, lane = tid & 63, w = tid >> 6;
  const int f32 = probe_f32(wdet, tid);
  constexpr int SK = 72;
  __shared__ __align__(16) bf16 Ks[2][64 * SK];   // [buf][key][e]
  __shared__ __align__(16) bf16 Vs[2][64 * SK];   // [buf][d][key]
  const int quad = lane >> 4, lm = lane & 15;

  const int L = (int)blockIdx.x + 64 * (int)blockIdx.y + 512 * (int)blockIdx.z;
  const int xcd = L & 7, slot0 = L >> 3;
  const int half = slot0 >> 6, sp = slot0 & 63;
  const int p = half ? 63 - sp : sp;
  const int hp = xcd * 2 + half;       // 0..15
  const int b = hp >> 3, h = hp & 7;

  const int Q0 = p * 64;
  const int qbase = Q0 + w * 16;
  const int last = p;                  // tiles 0..p

  // Q B-frags (persistent): qf[ks] = B[e=quad*8+j+ks*32][q=lm]
  bf16x8 qf[2];
  {
    const bf16* qp =
        Qt + ((size_t)b * Nn + qbase + lm) * Ee + h * HD + quad * 8;
    qf[0] = *(const bf16x8*)qp;
    qf[1] = *(const bf16x8*)(qp + 32);
  }
  floatx4 accO[4];
#pragma unroll
  for (int df = 0; df < 4; ++df) accO[df] = (floatx4){0.f, 0.f, 0.f, 0.f};
  float lsum = 0.f;

  // staging: r0 = tid>>3 in [0,32), g = tid&7; rows r0 and r0+32
  const int r0 = tid >> 3, g = tid & 7;
  const int sslot = ((g + r0) & 7) * 8;           // rotate swizzle
  const bf16* kp0 = Kt + ((size_t)b * Nn + r0) * Ee + h * HD + g * 8;
  const bf16* kp1 = kp0 + (size_t)32 * Ee;
  const bf16* vp0 = Ve + ((size_t)b * Ee + h * HD + r0) * Nn + g * 8;
  const bf16* vp1 = vp0 + (size_t)32 * Nn;

  // QK A-row permutation base: row R = quad*8 + 4*(f&1) + (lm&3) + 32*(f>>1)
  const int rbase = ((lm >> 2) << 3) | (lm & 3);

  // two register prefetch sets; all indices compile-time (rule #20)
  bf16x8 ka[2], kb[2], va[2], vb[2];
#define LOADT(s)                                                   \
  do {                                                             \
    ka[s] = *(const bf16x8*)kp0; kb[s] = *(const bf16x8*)kp1;      \
    va[s] = *(const bf16x8*)vp0; vb[s] = *(const bf16x8*)vp1;      \
    kp0 += (size_t)64 * Ee; kp1 += (size_t)64 * Ee;                \
    vp0 += 64; vp1 += 64;                                          \
  } while (0)
#define STAGET(s, buf)                                             \
  do {                                                             \
    *(bf16x8*)&Ks[buf][r0 * SK + sslot] = ka[s];                   \
    *(bf16x8*)&Ks[buf][(r0 + 32) * SK + sslot] = kb[s];            \
    *(bf16x8*)&Vs[buf][r0 * SK + sslot] = va[s];                   \
    *(bf16x8*)&Vs[buf][(r0 + 32) * SK + sslot] = vb[s];            \
  } while (0)

  // prologue: tile0 -> set0 -> LDS[0]; tile1 -> set1 (stays in regs)
  LOADT(0);
  if (last >= 1) LOADT(1);
  STAGET(0, 0);          // vmcnt waits only on set0's 4 loads
  __syncthreads();

#pragma unroll 1
  for (int kt = 0; kt <= last; kt += 2) {
#pragma unroll
    for (int u = 0; u < 2; ++u) {            // u is compile-time after unroll
      const int t = kt + u;
      if (u == 1 && t > last) break;         // block-uniform tail skip
      const int k0 = t * 64;
      if (t + 2 <= last) LOADT(u);           // 2-deep prefetch
      const bool skip = k0 > qbase + 15;     // wave-uniform: fully masked

      bf16x8 pb[2];
      if (!skip) {
        // S^T = K Q^T with permuted A-rows
        floatx4 accS[4];
#pragma unroll
        for (int f = 0; f < 4; ++f) accS[f] = (floatx4){0.f, 0.f, 0.f, 0.f};
        __builtin_amdgcn_s_setprio(1);
#pragma unroll
        for (int ks = 0; ks < 2; ++ks)
#pragma unroll
          for (int f = 0; f < 4; ++f) {
            const int R = rbase + ((f & 1) << 2) + ((f >> 1) << 5);
            const int sl = (ks * 4 + quad + R) & 7;
            bf16x8 ak = *(const bf16x8*)&Ks[u][R * SK + sl * 8];
            accS[f] = __builtin_amdgcn_mfma_f32_16x16x32_bf16(
                ak, qf[ks], accS[f], 0, 0, 0);
          }
        __builtin_amdgcn_s_setprio(0);
        // softmax + pack: key = k0 + g2*32 + quad*8 + jp*2; q = qbase+lm
        const bool maskt = (k0 + 63 > qbase);
        if (!maskt) {
          // mask-free fast path (vast majority of tiles)
          float la = 0.f, lb = 0.f;
#pragma unroll
          for (int g2 = 0; g2 < 2; ++g2) {
            union { unsigned pk[4]; bf16x8 v; } uu;
#pragma unroll
            for (int jp = 0; jp < 4; ++jp) {
              const int fidx = g2 * 2 + (jp >> 1);
              const int re = (jp & 1) * 2;
              float p0 = fast_exp2(accS[fidx][re]);
              float p1 = fast_exp2(accS[fidx][re + 1]);
              la += p0; lb += p1;
              uu.pk[jp] = pack_bf16_2(p0, p1);
            }
            pb[g2] = uu.v;
          }
          lsum += la + lb;
        } else {
          // diagonal tile: per-element causal zeroing
          const int qg = qbase + lm;
          float la = 0.f, lb = 0.f;
#pragma unroll
          for (int g2 = 0; g2 < 2; ++g2) {
            union { unsigned pk[4]; bf16x8 v; } uu;
#pragma unroll
            for (int jp = 0; jp < 4; ++jp) {
              const int fidx = g2 * 2 + (jp >> 1);
              const int re = (jp & 1) * 2;
              const int key0 = k0 + g2 * 32 + quad * 8 + jp * 2;
              float p0 = fast_exp2(accS[fidx][re]);
              float p1 = fast_exp2(accS[fidx][re + 1]);
              if (key0 > qg) p0 = 0.f;
              if (key0 + 1 > qg) p1 = 0.f;
              la += p0; lb += p1;
              uu.pk[jp] = pack_bf16_2(p0, p1);
            }
            pb[g2] = uu.v;
          }
          lsum += la + lb;
        }
      }
      // stage tile t+1 (reg set u^1) into the other LDS buffer; vmcnt here
      // waits only on set u^1's loads (issued >1 full tile ago)
      if (t + 1 <= last) STAGET(u ^ 1, u ^ 1);
      if (!skip) {
        // O^T += V^T P^T at K=32: A[d=df*16+lm][key=g2*32+quad*8+j] (b128)
        __builtin_amdgcn_s_setprio(1);
#pragma unroll
        for (int g2 = 0; g2 < 2; ++g2)
#pragma unroll
          for (int df = 0; df < 4; ++df) {
            const int Rv = df * 16 + lm;
            const int sl = (g2 * 4 + quad + Rv) & 7;
            bf16x8 av = *(const bf16x8*)&Vs[u][Rv * SK + sl * 8];
            accO[df] = __builtin_amdgcn_mfma_f32_16x16x32_bf16(
                av, pb[g2], accO[df], 0, 0, 0);
          }
        __builtin_amdgcn_s_setprio(0);
      }
      __syncthreads();  // buf u reads done everywhere; buf u^1 fully staged
    }
  }
#undef LOADT
#undef STAGET

  // l(q) split across the 4 quads -> reduce lanes lm+16k
  lsum += __shfl_xor(lsum, 16);
  lsum += __shfl_xor(lsum, 32);

  // epilogue: accO[df] rows d = df*16+quad*4+r, col q = qbase+lm
  const float inv = 1.0f / lsum;
  const int qg = qbase + lm;
#pragma unroll
  for (int df = 0; df < 4; ++df) {
#pragma unroll
    for (int r = 0; r < 4; ++r) {
      int d = h * HD + df * 16 + quad * 4 + r;
      size_t off = ((size_t)b * Ee + d) * Nn + qg;
      if (!f32) ((bf16*)Out)[off] = (bf16)(accO[df][r] * inv);
      else      ((float*)Out)[off] = accO[df][r] * inv;
    }
  }
}

// ---------------------------------------------------------------- launch
extern "C" void kernel_launch(void* const* d_in, const int* in_sizes, int n_in,
                              void* d_out, int out_size, void* d_ws,
                              size_t ws_size, hipStream_t stream) {
  const void* q  = d_in[0];
  const void* k  = d_in[1];
  const void* Wq = d_in[2];
  const void* bq = d_in[3];
  const void* Wk = d_in[4];
  const void* bk = d_in[5];
  const void* Wv = d_in[6];
  const void* bv = d_in[7];

  const size_t SZ = (size_t)B_ * Nn * Cc;  // 4M elems = 8MB bf16 per region
  // ws: [pad 1KB][Xtq 8MB][Qt 8MB][Kt 8MB][Vh 8MB if room].
  // d_out (16MB when fp32): lower 8MB = Xtk scratch, upper 8MB = bf16 W/bias
  // copies; both dead before attn writes the final output.
  bf16* Xtq  = (bf16*)((char*)d_ws + 1024);
  bf16* Qt   = Xtq + SZ;
  bf16* Kt   = Qt + SZ;
  bf16* Xtk  = (bf16*)d_out;
  bf16* Wb   = (bf16*)((char*)d_out + 8 * 1024 * 1024);
  bf16* Wqb = Wb,            *Wkb = Wb + WSEG,    *Wvb = Wb + 2 * WSEG;
  bf16* bqb = Wb + 3 * WSEG, *bkb = bqb + 512,    *bvb = bqb + 1024;

  // Vh: its own region when the workspace is big enough -> one fused gemm
  // launch (no Q/K vs V serialization); else alias Xtq + two launches.
  const size_t need = 1024 + 4 * SZ * sizeof(bf16);
  const bool sep = ws_size >= need;
  bf16* Vh = sep ? (Kt + SZ) : Xtq;

  prep<<<dim3(64, 8, 5), 256, 0, stream>>>(
      q, k, Xtq, Xtk,
      (const float*)Wq, (const float*)Wk, (const float*)Wv,
      (const float*)bq, (const float*)bk, (const float*)bv, Wb);
  if (sep) {
    gemm3<<<dim3(32, 4, 6), 256, 0, stream>>>(
        Xtq, Xtk, Wq, Wqb, Wk, Wkb, Wv, Wvb,
        bq, bqb, bk, bkb, bv, bvb, Qt, Kt, Vh, 0);
  } else {
    // Q+K projections (read Xtq/Xtk; no aliasing within the launch)
    gemm3<<<dim3(32, 4, 4), 256, 0, stream>>>(
        Xtq, Xtk, Wq, Wqb, Wk, Wkb, Wv, Wvb,
        bq, bqb, bk, bkb, bv, bvb, Qt, Kt, Vh, 0);
    // V projection (writes Vh == Xtq region) - separate launch, serialized
    gemm3<<<dim3(32, 4, 2), 256, 0, stream>>>(
        Xtq, Xtk, Wq, Wqb, Wk, Wkb, Wv, Wvb,
        bq, bqb, bk, bkb, bv, bvb, Qt, Kt, Vh, 4);
  }
  attn<<<dim3(64, NH, B_), 256, 0, stream>>>(
      Qt, Kt, Vh, d_out, (const unsigned short*)Wq);
}